// Round 1
// baseline (619.502 us; speedup 1.0000x reference)
//
#include <hip/hip_runtime.h>
#include <hip/hip_bf16.h>
#include <cstdint>
#include <cstddef>

// Problem constants
#define NT 8192
#define DD 512
#define HH 2048
#define NE 4

typedef short short8 __attribute__((ext_vector_type(8)));
typedef float floatx4 __attribute__((ext_vector_type(4)));

static __device__ __forceinline__ unsigned short f2bf(float f) {
    union { float f; uint32_t u; } v; v.f = f;
    uint32_t u = v.u;
    u += 0x7FFFu + ((u >> 16) & 1u);   // round-to-nearest-even
    return (unsigned short)(u >> 16);
}

// ---------------- cast h (fp32 -> bf16), row-major [NT][DD] ----------------
__global__ void k_cast_h(const float* __restrict__ h, unsigned short* __restrict__ hb) {
    int i = (blockIdx.x * 256 + threadIdx.x) * 4;
    float4 v = *(const float4*)(h + i);
    ushort4 o;
    o.x = f2bf(v.x); o.y = f2bf(v.y); o.z = f2bf(v.z); o.w = f2bf(v.w);
    *(ushort4*)(hb + i) = o;
}

// ------------- batched transpose + cast: in[b][R][C] f32 -> out[b][C][R] bf16 -------------
__global__ void k_transpose_cast(const float* __restrict__ in, unsigned short* __restrict__ out,
                                 int R, int C) {
    int b = blockIdx.z;
    in  += (size_t)b * R * C;
    out += (size_t)b * R * C;
    __shared__ float tile[32][33];
    int tx = threadIdx.x & 31, ty = threadIdx.x >> 5;
    int r0 = blockIdx.y * 32, c0 = blockIdx.x * 32;
#pragma unroll
    for (int it = 0; it < 4; it++) {
        int r = ty + it * 8;
        tile[r][tx] = in[(size_t)(r0 + r) * C + c0 + tx];
    }
    __syncthreads();
#pragma unroll
    for (int it = 0; it < 4; it++) {
        int r = ty + it * 8;  // local col index of input = local row of output
        out[(size_t)(c0 + r) * R + r0 + tx] = f2bf(tile[tx][r]);
    }
}

// ---------------- gating: fp32 logits, exact top-2, softmax over top-2 ----------------
// ctl layout (ints): [0..3]=counts, [4..7]=cursors, [8..12]=offsets
__global__ void k_gate(const float* __restrict__ h, const float* __restrict__ wg,
                       int* __restrict__ sel, float* __restrict__ gv, int* __restrict__ ctl) {
    int wid = threadIdx.x >> 6, lane = threadIdx.x & 63;
    int n = blockIdx.x * 4 + wid;
    const float* hr = h + (size_t)n * DD;
    int d0 = lane * 8;
    float hv[8];
    *(float4*)(hv)     = *(const float4*)(hr + d0);
    *(float4*)(hv + 4) = *(const float4*)(hr + d0 + 4);
    float a0 = 0.f, a1 = 0.f, a2 = 0.f, a3 = 0.f;
#pragma unroll
    for (int j = 0; j < 8; j++) {
        float4 w = *(const float4*)(wg + (size_t)(d0 + j) * 4);
        a0 += hv[j] * w.x; a1 += hv[j] * w.y; a2 += hv[j] * w.z; a3 += hv[j] * w.w;
    }
#pragma unroll
    for (int off = 32; off; off >>= 1) {
        a0 += __shfl_xor(a0, off);
        a1 += __shfl_xor(a1, off);
        a2 += __shfl_xor(a2, off);
        a3 += __shfl_xor(a3, off);
    }
    if (lane == 0) {
        float v[4] = {a0, a1, a2, a3};
        int e0 = 0; float b = v[0];
#pragma unroll
        for (int e = 1; e < 4; e++) if (v[e] > b) { b = v[e]; e0 = e; }
        int e1 = -1; float b2 = -1e30f;
#pragma unroll
        for (int e = 0; e < 4; e++) if (e != e0 && v[e] > b2) { b2 = v[e]; e1 = e; }
        float x = expf(b2 - b);
        float s = 1.f + x;
        sel[2 * n] = e0; sel[2 * n + 1] = e1;
        gv[2 * n] = 1.f / s; gv[2 * n + 1] = x / s;
        atomicAdd(ctl + e0, 1);
        atomicAdd(ctl + e1, 1);
    }
}

__global__ void k_offsets(int* __restrict__ ctl) {
    if (threadIdx.x == 0) {
        int o = 0;
#pragma unroll
        for (int e = 0; e < 4; e++) { ctl[8 + e] = o; o += ctl[e]; }
        ctl[12] = o;
    }
}

__global__ void k_build(const int* __restrict__ sel, const float* __restrict__ gv,
                        int* __restrict__ ctl, int* __restrict__ rtok, float* __restrict__ rgte) {
    int n = blockIdx.x * 256 + threadIdx.x;
    if (n >= NT) return;
#pragma unroll
    for (int k = 0; k < 2; k++) {
        int e = sel[2 * n + k];
        int pos = atomicAdd(ctl + 4 + e, 1);
        int slot = ctl[8 + e] + pos;
        rtok[slot] = n;
        rgte[slot] = gv[2 * n + k];
    }
}

// ---------------- grouped GEMM 1: mid = relu(gather(h) @ w1[e] + b1[e]) ----------------
#define BK 32
#define LDSS 40   // padded LDS stride (bf16 elems): 80 B rows -> 2-way bank aliasing only

__global__ __launch_bounds__(256) void k_ffn1(
    const unsigned short* __restrict__ hb, const unsigned short* __restrict__ w1t,
    const float* __restrict__ b1, const int* __restrict__ ctl,
    const int* __restrict__ rtok, unsigned short* __restrict__ mid) {
    int e = blockIdx.z;
    int base = ctl[8 + e];
    int cnt = ctl[9 + e] - base;
    int m0 = blockIdx.y * 128;
    if (m0 >= cnt) return;
    int n0 = blockIdx.x * 128;

    __shared__ unsigned short As[128 * LDSS];
    __shared__ unsigned short Bs[128 * LDSS];
    __shared__ int toks[128];

    int t = threadIdx.x;
    if (t < 128) {
        int r = m0 + t; if (r >= cnt) r = cnt - 1;
        toks[t] = rtok[base + r];
    }
    __syncthreads();

    const unsigned short* wB = w1t + (size_t)e * HH * DD;
    int lr = t >> 1;          // staging row 0..127
    int lc = (t & 1) * 16;    // staging col 0 / 16
    int wid = t >> 6, lane = t & 63;
    int wm = (wid & 1) * 64, wn = (wid >> 1) * 64;
    int lrow = lane & 15, quad = lane >> 4;

    floatx4 acc[4][4];
#pragma unroll
    for (int i = 0; i < 4; i++)
#pragma unroll
        for (int j = 0; j < 4; j++) acc[i][j] = (floatx4)0.f;

    for (int kk = 0; kk < DD; kk += BK) {
        const unsigned short* pa = hb + (size_t)toks[lr] * DD + kk + lc;
        *(uint4*)&As[lr * LDSS + lc]     = *(const uint4*)pa;
        *(uint4*)&As[lr * LDSS + lc + 8] = *(const uint4*)(pa + 8);
        const unsigned short* pb = wB + (size_t)(n0 + lr) * DD + kk + lc;
        *(uint4*)&Bs[lr * LDSS + lc]     = *(const uint4*)pb;
        *(uint4*)&Bs[lr * LDSS + lc + 8] = *(const uint4*)(pb + 8);
        __syncthreads();
        short8 af[4], bf[4];
#pragma unroll
        for (int i = 0; i < 4; i++)
            af[i] = *(const short8*)&As[(wm + 16 * i + lrow) * LDSS + quad * 8];
#pragma unroll
        for (int j = 0; j < 4; j++)
            bf[j] = *(const short8*)&Bs[(wn + 16 * j + lrow) * LDSS + quad * 8];
#pragma unroll
        for (int i = 0; i < 4; i++)
#pragma unroll
            for (int j = 0; j < 4; j++)
                acc[i][j] = __builtin_amdgcn_mfma_f32_16x16x32_bf16(af[i], bf[j], acc[i][j], 0, 0, 0);
        __syncthreads();
    }

    // epilogue: bias + relu + bf16 store (D layout: col=lane&15, row=quad*4+reg)
#pragma unroll
    for (int j = 0; j < 4; j++) {
        int hcol = n0 + wn + 16 * j + lrow;
        float bias = b1[e * HH + hcol];
#pragma unroll
        for (int i = 0; i < 4; i++) {
#pragma unroll
            for (int r = 0; r < 4; r++) {
                int m = wm + 16 * i + quad * 4 + r;
                if (m0 + m < cnt) {
                    float v = acc[i][j][r] + bias;
                    v = v > 0.f ? v : 0.f;
                    mid[(size_t)(base + m0 + m) * HH + hcol] = f2bf(v);
                }
            }
        }
    }
}

// ---------------- grouped GEMM 2: out += gate * (mid @ w2[e] + b2[e]) ----------------
__global__ __launch_bounds__(256) void k_ffn2(
    const unsigned short* __restrict__ mid, const unsigned short* __restrict__ w2t,
    const float* __restrict__ b2, const int* __restrict__ ctl,
    const int* __restrict__ rtok, const float* __restrict__ rgte,
    float* __restrict__ out) {
    int e = blockIdx.z;
    int base = ctl[8 + e];
    int cnt = ctl[9 + e] - base;
    int m0 = blockIdx.y * 128;
    if (m0 >= cnt) return;
    int n0 = blockIdx.x * 128;

    __shared__ unsigned short As[128 * LDSS];
    __shared__ unsigned short Bs[128 * LDSS];
    __shared__ int toks[128];
    __shared__ float gts[128];

    int t = threadIdx.x;
    if (t < 128) {
        int r = m0 + t; if (r >= cnt) r = cnt - 1;
        toks[t] = rtok[base + r];
        gts[t] = rgte[base + r];
    }
    __syncthreads();

    const unsigned short* wB = w2t + (size_t)e * DD * HH;
    int lr = t >> 1;
    int lc = (t & 1) * 16;
    int wid = t >> 6, lane = t & 63;
    int wm = (wid & 1) * 64, wn = (wid >> 1) * 64;
    int lrow = lane & 15, quad = lane >> 4;

    // A rows are slot-contiguous (mid already expert-compacted); clamp to stay in-buffer
    int arow = m0 + lr; if (arow >= cnt) arow = cnt - 1;
    const unsigned short* pa0 = mid + (size_t)(base + arow) * HH;

    floatx4 acc[4][4];
#pragma unroll
    for (int i = 0; i < 4; i++)
#pragma unroll
        for (int j = 0; j < 4; j++) acc[i][j] = (floatx4)0.f;

    for (int kk = 0; kk < HH; kk += BK) {
        *(uint4*)&As[lr * LDSS + lc]     = *(const uint4*)(pa0 + kk + lc);
        *(uint4*)&As[lr * LDSS + lc + 8] = *(const uint4*)(pa0 + kk + lc + 8);
        const unsigned short* pb = wB + (size_t)(n0 + lr) * HH + kk + lc;
        *(uint4*)&Bs[lr * LDSS + lc]     = *(const uint4*)pb;
        *(uint4*)&Bs[lr * LDSS + lc + 8] = *(const uint4*)(pb + 8);
        __syncthreads();
        short8 af[4], bf[4];
#pragma unroll
        for (int i = 0; i < 4; i++)
            af[i] = *(const short8*)&As[(wm + 16 * i + lrow) * LDSS + quad * 8];
#pragma unroll
        for (int j = 0; j < 4; j++)
            bf[j] = *(const short8*)&Bs[(wn + 16 * j + lrow) * LDSS + quad * 8];
#pragma unroll
        for (int i = 0; i < 4; i++)
#pragma unroll
            for (int j = 0; j < 4; j++)
                acc[i][j] = __builtin_amdgcn_mfma_f32_16x16x32_bf16(af[i], bf[j], acc[i][j], 0, 0, 0);
        __syncthreads();
    }

#pragma unroll
    for (int j = 0; j < 4; j++) {
        int d = n0 + wn + 16 * j + lrow;
        float b2v = b2[e * DD + d];
#pragma unroll
        for (int i = 0; i < 4; i++) {
#pragma unroll
            for (int r = 0; r < 4; r++) {
                int m = wm + 16 * i + quad * 4 + r;
                if (m0 + m < cnt) {
                    float v = (acc[i][j][r] + b2v) * gts[m];
                    atomicAdd(out + (size_t)toks[m] * DD + d, v);
                }
            }
        }
    }
}

extern "C" void kernel_launch(void* const* d_in, const int* in_sizes, int n_in,
                              void* d_out, int out_size, void* d_ws, size_t ws_size,
                              hipStream_t stream) {
    const float* h  = (const float*)d_in[0];
    const float* wg = (const float*)d_in[1];
    const float* w1 = (const float*)d_in[2];
    const float* b1 = (const float*)d_in[3];
    const float* w2 = (const float*)d_in[4];
    const float* b2 = (const float*)d_in[5];
    float* out = (float*)d_out;

    char* ws = (char*)d_ws;
    size_t off = 0;
    auto alloc = [&](size_t bytes) -> void* {
        void* p = ws + off;
        off += (bytes + 255) & ~(size_t)255;
        return p;
    };
    unsigned short* hb  = (unsigned short*)alloc((size_t)NT * DD * 2);
    unsigned short* w1t = (unsigned short*)alloc((size_t)NE * HH * DD * 2);
    unsigned short* w2t = (unsigned short*)alloc((size_t)NE * DD * HH * 2);
    int*   sel  = (int*)alloc((size_t)NT * 2 * 4);
    float* gv   = (float*)alloc((size_t)NT * 2 * 4);
    int*   ctl  = (int*)alloc(256);
    int*   rtok = (int*)alloc((size_t)NT * 2 * 4);
    float* rgte = (float*)alloc((size_t)NT * 2 * 4);
    unsigned short* mid = (unsigned short*)alloc((size_t)NT * 2 * HH * 2);

    hipMemsetAsync(ctl, 0, 256, stream);
    hipMemsetAsync(d_out, 0, (size_t)out_size * 4, stream);

    k_cast_h<<<dim3(NT * DD / 1024), 256, 0, stream>>>(h, hb);
    k_transpose_cast<<<dim3(HH / 32, DD / 32, NE), 256, 0, stream>>>(w1, w1t, DD, HH);
    k_transpose_cast<<<dim3(DD / 32, HH / 32, NE), 256, 0, stream>>>(w2, w2t, HH, DD);
    k_gate<<<dim3(NT / 4), 256, 0, stream>>>(h, wg, sel, gv, ctl);
    k_offsets<<<1, 64, 0, stream>>>(ctl);
    k_build<<<dim3(NT / 256), 256, 0, stream>>>(sel, gv, ctl, rtok, rgte);
    k_ffn1<<<dim3(HH / 128, NT / 128, NE), 256, 0, stream>>>(hb, w1t, b1, ctl, rtok, mid);
    k_ffn2<<<dim3(DD / 128, NT / 128, NE), 256, 0, stream>>>(mid, w2t, b2, ctl, rtok, rgte, out);
}

// Round 2
// 305.919 us; speedup vs baseline: 2.0251x; 2.0251x over previous
//
#include <hip/hip_runtime.h>
#include <hip/hip_bf16.h>
#include <cstdint>
#include <cstddef>

// Problem constants
#define NT 8192
#define DD 512
#define HH 2048
#define NE 4

typedef short short8 __attribute__((ext_vector_type(8)));
typedef float floatx4 __attribute__((ext_vector_type(4)));

static __device__ __forceinline__ unsigned short f2bf(float f) {
    union { float f; uint32_t u; } v; v.f = f;
    uint32_t u = v.u;
    u += 0x7FFFu + ((u >> 16) & 1u);   // round-to-nearest-even
    return (unsigned short)(u >> 16);
}
static __device__ __forceinline__ float bf2f(unsigned short u) {
    union { uint32_t u; float f; } v; v.u = ((uint32_t)u) << 16; return v.f;
}

// async global->LDS, 16B per lane. LDS dest MUST be wave-uniform base + lane*16.
static __device__ __forceinline__ void gld_lds16(const unsigned short* g, unsigned short* l) {
    __builtin_amdgcn_global_load_lds(
        (const __attribute__((address_space(1))) void*)g,
        (__attribute__((address_space(3))) void*)l, 16, 0, 0);
}

// ---------------- cast h (fp32 -> bf16), row-major [NT][DD] ----------------
__global__ void k_cast_h(const float* __restrict__ h, unsigned short* __restrict__ hb) {
    int i = (blockIdx.x * 256 + threadIdx.x) * 4;
    float4 v = *(const float4*)(h + i);
    ushort4 o;
    o.x = f2bf(v.x); o.y = f2bf(v.y); o.z = f2bf(v.z); o.w = f2bf(v.w);
    *(ushort4*)(hb + i) = o;
}

// ------------- batched transpose + cast: in[b][R][C] f32 -> out[b][C][R] bf16 -------------
__global__ void k_transpose_cast(const float* __restrict__ in, unsigned short* __restrict__ out,
                                 int R, int C) {
    int b = blockIdx.z;
    in  += (size_t)b * R * C;
    out += (size_t)b * R * C;
    __shared__ float tile[32][33];
    int tx = threadIdx.x & 31, ty = threadIdx.x >> 5;
    int r0 = blockIdx.y * 32, c0 = blockIdx.x * 32;
#pragma unroll
    for (int it = 0; it < 4; it++) {
        int r = ty + it * 8;
        tile[r][tx] = in[(size_t)(r0 + r) * C + c0 + tx];
    }
    __syncthreads();
#pragma unroll
    for (int it = 0; it < 4; it++) {
        int r = ty + it * 8;
        out[(size_t)(c0 + r) * R + r0 + tx] = f2bf(tile[tx][r]);
    }
}

// ---------------- gating: fp32 logits, exact top-2, softmax over top-2. NO atomics. ----------------
__global__ void k_gate(const float* __restrict__ h, const float* __restrict__ wg,
                       int* __restrict__ sel, float* __restrict__ gv) {
    int wid = threadIdx.x >> 6, lane = threadIdx.x & 63;
    int n = blockIdx.x * 4 + wid;
    const float* hr = h + (size_t)n * DD;
    int d0 = lane * 8;
    float hv[8];
    *(float4*)(hv)     = *(const float4*)(hr + d0);
    *(float4*)(hv + 4) = *(const float4*)(hr + d0 + 4);
    float a0 = 0.f, a1 = 0.f, a2 = 0.f, a3 = 0.f;
#pragma unroll
    for (int j = 0; j < 8; j++) {
        float4 w = *(const float4*)(wg + (size_t)(d0 + j) * 4);
        a0 += hv[j] * w.x; a1 += hv[j] * w.y; a2 += hv[j] * w.z; a3 += hv[j] * w.w;
    }
#pragma unroll
    for (int off = 32; off; off >>= 1) {
        a0 += __shfl_xor(a0, off);
        a1 += __shfl_xor(a1, off);
        a2 += __shfl_xor(a2, off);
        a3 += __shfl_xor(a3, off);
    }
    if (lane == 0) {
        float v[4] = {a0, a1, a2, a3};
        int e0 = 0; float b = v[0];
#pragma unroll
        for (int e = 1; e < 4; e++) if (v[e] > b) { b = v[e]; e0 = e; }
        int e1 = -1; float b2 = -1e30f;
#pragma unroll
        for (int e = 0; e < 4; e++) if (e != e0 && v[e] > b2) { b2 = v[e]; e1 = e; }
        float x = expf(b2 - b);
        float s = 1.f + x;
        sel[2 * n] = e0; sel[2 * n + 1] = e1;
        gv[2 * n] = 1.f / s; gv[2 * n + 1] = x / s;
    }
}

// ---------------- single-block scan: counts -> offsets -> deterministic slot assignment ----------------
// ctl: [8..11]=expert base, [12]=total
__global__ __launch_bounds__(256) void k_scan(const int* __restrict__ sel, const float* __restrict__ gv,
                                              int* __restrict__ ctl, int* __restrict__ rtok,
                                              float* __restrict__ rgte, int* __restrict__ slotof) {
    __shared__ int cnt[4][256];
    __shared__ int ebase[4];
    int t = threadIdx.x;
    int c[4] = {0, 0, 0, 0};
    int selloc[64];
#pragma unroll 4
    for (int i = 0; i < 64; i++) {
        int s = sel[t * 64 + i];
        selloc[i] = s;
        c[s]++;
    }
#pragma unroll
    for (int e = 0; e < 4; e++) cnt[e][t] = c[e];
    __syncthreads();
    // Hillis-Steele inclusive scan over 256 threads, 4 experts in parallel
    for (int step = 1; step < 256; step <<= 1) {
        int v[4];
#pragma unroll
        for (int e = 0; e < 4; e++) v[e] = (t >= step) ? cnt[e][t - step] : 0;
        __syncthreads();
#pragma unroll
        for (int e = 0; e < 4; e++) cnt[e][t] += v[e];
        __syncthreads();
    }
    if (t == 0) {
        int o = 0;
#pragma unroll
        for (int e = 0; e < 4; e++) { ebase[e] = o; ctl[8 + e] = o; o += cnt[e][255]; }
        ctl[12] = o;
    }
    __syncthreads();
    int pos[4];
#pragma unroll
    for (int e = 0; e < 4; e++) pos[e] = ebase[e] + cnt[e][t] - c[e];  // exclusive prefix
#pragma unroll 4
    for (int i = 0; i < 64; i++) {
        int idx = t * 64 + i;          // = 2*n + k
        int e = selloc[i];
        int s = pos[e]++;
        rtok[s] = idx >> 1;
        rgte[s] = gv[idx];
        slotof[idx] = s;
    }
}

// ---------------- grouped GEMM 1: mid = relu(gather(h) @ w1[e] + b1[e]) ----------------
#define BK 32

__global__ __launch_bounds__(256) void k_ffn1(
    const unsigned short* __restrict__ hb, const unsigned short* __restrict__ w1t,
    const float* __restrict__ b1, const int* __restrict__ ctl,
    const int* __restrict__ rtok, unsigned short* __restrict__ mid) {
    int e = blockIdx.z;
    int base = ctl[8 + e];
    int cnt = ctl[9 + e] - base;
    int m0 = blockIdx.y * 128;
    if (m0 >= cnt) return;
    int n0 = blockIdx.x * 128;

    __shared__ unsigned short As[128 * BK];   // 8 KB, unpadded (global_load_lds layout)
    __shared__ unsigned short Bs[128 * BK];
    __shared__ int toks[128];

    int t = threadIdx.x;
    if (t < 128) {
        int r = m0 + t; if (r >= cnt) r = cnt - 1;
        toks[t] = rtok[base + r];
    }
    __syncthreads();

    const unsigned short* wB = w1t + (size_t)e * HH * DD;
    int wid = t >> 6, lane = t & 63;
    int wm = (wid & 1) * 64, wn = (wid >> 1) * 64;
    int lrow = lane & 15, quad = lane >> 4;

    // staging geometry: wave stages 16 rows (64B each) per chunk, 2 chunks per matrix
    int srow = lane >> 2;           // 0..15
    int scol = (lane & 3) * 8;      // element offset of 16B unit
    unsigned short* lpA0 = As + wid * 16 * BK + lane * 8;
    unsigned short* lpA1 = lpA0 + 64 * BK;
    unsigned short* lpB0 = Bs + wid * 16 * BK + lane * 8;
    unsigned short* lpB1 = lpB0 + 64 * BK;
    const unsigned short* gA0 = hb + (size_t)toks[wid * 16 + srow] * DD + scol;
    const unsigned short* gA1 = hb + (size_t)toks[64 + wid * 16 + srow] * DD + scol;
    const unsigned short* gB0 = wB + (size_t)(n0 + wid * 16 + srow) * DD + scol;
    const unsigned short* gB1 = wB + (size_t)(n0 + 64 + wid * 16 + srow) * DD + scol;

    floatx4 acc[4][4];
#pragma unroll
    for (int i = 0; i < 4; i++)
#pragma unroll
        for (int j = 0; j < 4; j++) acc[i][j] = (floatx4)0.f;

    for (int kk = 0; kk < DD; kk += BK) {
        gld_lds16(gA0 + kk, lpA0);
        gld_lds16(gA1 + kk, lpA1);
        gld_lds16(gB0 + kk, lpB0);
        gld_lds16(gB1 + kk, lpB1);
        __syncthreads();
        short8 af[4], bf[4];
#pragma unroll
        for (int i = 0; i < 4; i++)
            af[i] = *(const short8*)&As[(wm + 16 * i + lrow) * BK + quad * 8];
#pragma unroll
        for (int j = 0; j < 4; j++)
            bf[j] = *(const short8*)&Bs[(wn + 16 * j + lrow) * BK + quad * 8];
#pragma unroll
        for (int i = 0; i < 4; i++)
#pragma unroll
            for (int j = 0; j < 4; j++)
                acc[i][j] = __builtin_amdgcn_mfma_f32_16x16x32_bf16(af[i], bf[j], acc[i][j], 0, 0, 0);
        __syncthreads();
    }

    // epilogue: bias + relu + bf16 store (D layout: col=lane&15, row=quad*4+reg)
#pragma unroll
    for (int j = 0; j < 4; j++) {
        int hcol = n0 + wn + 16 * j + lrow;
        float bias = b1[e * HH + hcol];
#pragma unroll
        for (int i = 0; i < 4; i++) {
#pragma unroll
            for (int r = 0; r < 4; r++) {
                int m = wm + 16 * i + quad * 4 + r;
                if (m0 + m < cnt) {
                    float v = acc[i][j][r] + bias;
                    v = v > 0.f ? v : 0.f;
                    mid[(size_t)(base + m0 + m) * HH + hcol] = f2bf(v);
                }
            }
        }
    }
}

// ---------------- grouped GEMM 2: ybuf[slot] = gate * (mid @ w2[e] + b2[e]) ----------------
__global__ __launch_bounds__(256) void k_ffn2(
    const unsigned short* __restrict__ mid, const unsigned short* __restrict__ w2t,
    const float* __restrict__ b2, const int* __restrict__ ctl,
    const float* __restrict__ rgte, unsigned short* __restrict__ ybuf) {
    int e = blockIdx.z;
    int base = ctl[8 + e];
    int cnt = ctl[9 + e] - base;
    int m0 = blockIdx.y * 128;
    if (m0 >= cnt) return;
    int n0 = blockIdx.x * 128;

    __shared__ unsigned short As[128 * BK];
    __shared__ unsigned short Bs[128 * BK];
    __shared__ float gts[128];

    int t = threadIdx.x;
    if (t < 128) {
        int r = m0 + t; if (r >= cnt) r = cnt - 1;
        gts[t] = rgte[base + r];
    }
    __syncthreads();

    const unsigned short* wB = w2t + (size_t)e * DD * HH;
    int wid = t >> 6, lane = t & 63;
    int wm = (wid & 1) * 64, wn = (wid >> 1) * 64;
    int lrow = lane & 15, quad = lane >> 4;

    int srow = lane >> 2;
    int scol = (lane & 3) * 8;
    unsigned short* lpA0 = As + wid * 16 * BK + lane * 8;
    unsigned short* lpA1 = lpA0 + 64 * BK;
    unsigned short* lpB0 = Bs + wid * 16 * BK + lane * 8;
    unsigned short* lpB1 = lpB0 + 64 * BK;
    int rA0 = m0 + wid * 16 + srow;      if (rA0 >= cnt) rA0 = cnt - 1;
    int rA1 = m0 + 64 + wid * 16 + srow; if (rA1 >= cnt) rA1 = cnt - 1;
    const unsigned short* gA0 = mid + (size_t)(base + rA0) * HH + scol;
    const unsigned short* gA1 = mid + (size_t)(base + rA1) * HH + scol;
    const unsigned short* gB0 = wB + (size_t)(n0 + wid * 16 + srow) * HH + scol;
    const unsigned short* gB1 = wB + (size_t)(n0 + 64 + wid * 16 + srow) * HH + scol;

    floatx4 acc[4][4];
#pragma unroll
    for (int i = 0; i < 4; i++)
#pragma unroll
        for (int j = 0; j < 4; j++) acc[i][j] = (floatx4)0.f;

    for (int kk = 0; kk < HH; kk += BK) {
        gld_lds16(gA0 + kk, lpA0);
        gld_lds16(gA1 + kk, lpA1);
        gld_lds16(gB0 + kk, lpB0);
        gld_lds16(gB1 + kk, lpB1);
        __syncthreads();
        short8 af[4], bf[4];
#pragma unroll
        for (int i = 0; i < 4; i++)
            af[i] = *(const short8*)&As[(wm + 16 * i + lrow) * BK + quad * 8];
#pragma unroll
        for (int j = 0; j < 4; j++)
            bf[j] = *(const short8*)&Bs[(wn + 16 * j + lrow) * BK + quad * 8];
#pragma unroll
        for (int i = 0; i < 4; i++)
#pragma unroll
            for (int j = 0; j < 4; j++)
                acc[i][j] = __builtin_amdgcn_mfma_f32_16x16x32_bf16(af[i], bf[j], acc[i][j], 0, 0, 0);
        __syncthreads();
    }

#pragma unroll
    for (int j = 0; j < 4; j++) {
        int d = n0 + wn + 16 * j + lrow;
        float b2v = b2[e * DD + d];
#pragma unroll
        for (int i = 0; i < 4; i++) {
#pragma unroll
            for (int r = 0; r < 4; r++) {
                int m = wm + 16 * i + quad * 4 + r;
                if (m0 + m < cnt) {
                    float v = (acc[i][j][r] + b2v) * gts[m];
                    ybuf[(size_t)(base + m0 + m) * DD + d] = f2bf(v);
                }
            }
        }
    }
}

// ---------------- combine: out[n] = ybuf[slot(n,0)] + ybuf[slot(n,1)] ----------------
__global__ void k_combine(const unsigned short* __restrict__ ybuf, const int* __restrict__ slotof,
                          float* __restrict__ out) {
    int n = blockIdx.x;
    int c = threadIdx.x * 4;
    int sA = slotof[2 * n], sB = slotof[2 * n + 1];
    ushort4 a = *(const ushort4*)(ybuf + (size_t)sA * DD + c);
    ushort4 b = *(const ushort4*)(ybuf + (size_t)sB * DD + c);
    float4 o;
    o.x = bf2f(a.x) + bf2f(b.x);
    o.y = bf2f(a.y) + bf2f(b.y);
    o.z = bf2f(a.z) + bf2f(b.z);
    o.w = bf2f(a.w) + bf2f(b.w);
    *(float4*)(out + (size_t)n * DD + c) = o;
}

extern "C" void kernel_launch(void* const* d_in, const int* in_sizes, int n_in,
                              void* d_out, int out_size, void* d_ws, size_t ws_size,
                              hipStream_t stream) {
    const float* h  = (const float*)d_in[0];
    const float* wg = (const float*)d_in[1];
    const float* w1 = (const float*)d_in[2];
    const float* b1 = (const float*)d_in[3];
    const float* w2 = (const float*)d_in[4];
    const float* b2 = (const float*)d_in[5];
    float* out = (float*)d_out;

    char* ws = (char*)d_ws;
    size_t off = 0;
    auto alloc = [&](size_t bytes) -> void* {
        void* p = ws + off;
        off += (bytes + 255) & ~(size_t)255;
        return p;
    };
    unsigned short* hb  = (unsigned short*)alloc((size_t)NT * DD * 2);        // dead after ffn1
    unsigned short* w1t = (unsigned short*)alloc((size_t)NE * HH * DD * 2);   // dead after ffn1
    unsigned short* w2t = (unsigned short*)alloc((size_t)NE * DD * HH * 2);
    int*   sel    = (int*)alloc((size_t)NT * 2 * 4);
    float* gv     = (float*)alloc((size_t)NT * 2 * 4);
    int*   ctl    = (int*)alloc(256);
    int*   rtok   = (int*)alloc((size_t)NT * 2 * 4);
    float* rgte   = (float*)alloc((size_t)NT * 2 * 4);
    int*   slotof = (int*)alloc((size_t)NT * 2 * 4);
    unsigned short* mid = (unsigned short*)alloc((size_t)NT * 2 * HH * 2);
    // ybuf [NT*2][DD] bf16 (16.7 MB) aliases hb+w1t (16.7 MB), both dead before ffn2 runs
    unsigned short* ybuf = (unsigned short*)ws;

    k_cast_h<<<dim3(NT * DD / 1024), 256, 0, stream>>>(h, hb);
    k_transpose_cast<<<dim3(HH / 32, DD / 32, NE), 256, 0, stream>>>(w1, w1t, DD, HH);
    k_transpose_cast<<<dim3(DD / 32, HH / 32, NE), 256, 0, stream>>>(w2, w2t, HH, DD);
    k_gate<<<dim3(NT / 4), 256, 0, stream>>>(h, wg, sel, gv);
    k_scan<<<1, 256, 0, stream>>>(sel, gv, ctl, rtok, rgte, slotof);
    k_ffn1<<<dim3(HH / 128, NT / 128, NE), 256, 0, stream>>>(hb, w1t, b1, ctl, rtok, mid);
    k_ffn2<<<dim3(DD / 128, NT / 128, NE), 256, 0, stream>>>(mid, w2t, b2, ctl, rgte, ybuf);
    k_combine<<<dim3(NT), 128, 0, stream>>>(ybuf, slotof, out);
}

// Round 3
// 294.767 us; speedup vs baseline: 2.1017x; 1.0378x over previous
//
#include <hip/hip_runtime.h>
#include <hip/hip_bf16.h>
#include <cstdint>
#include <cstddef>

// Problem constants
#define NT 8192
#define DD 512
#define HH 2048
#define NE 4
#define BK 64          // K-tile (bf16 elems); 8 chunks of 16B per row
#define RP 136         // repack LDS stride (elems) — breaks bank alignment
#define SMEM_ELEMS 17408  // max(staging 2*128*64=16384, repack 128*136=17408)

typedef short short8 __attribute__((ext_vector_type(8)));
typedef float floatx4 __attribute__((ext_vector_type(4)));

static __device__ __forceinline__ unsigned short f2bf(float f) {
    union { float f; uint32_t u; } v; v.f = f;
    uint32_t u = v.u;
    u += 0x7FFFu + ((u >> 16) & 1u);   // round-to-nearest-even
    return (unsigned short)(u >> 16);
}
static __device__ __forceinline__ float bf2f(unsigned short u) {
    union { uint32_t u; float f; } v; v.u = ((uint32_t)u) << 16; return v.f;
}

// async global->LDS, 16B per lane. LDS dest = wave-uniform base + lane*16.
static __device__ __forceinline__ void gld_lds16(const unsigned short* g, unsigned short* l) {
    __builtin_amdgcn_global_load_lds(
        (const __attribute__((address_space(1))) void*)g,
        (__attribute__((address_space(3))) void*)l, 16, 0, 0);
}

// ------------- merged batched transpose + cast (w1 and w2 in one launch) -------------
// z in [0,4): w1 expert z: [DD][HH] -> w1t [HH][DD]
// z in [4,8): w2 expert z-4: [HH][DD] -> w2t [DD][HH]
__global__ void k_transpose_cast(const float* __restrict__ w1, unsigned short* __restrict__ w1t,
                                 const float* __restrict__ w2, unsigned short* __restrict__ w2t) {
    int z = blockIdx.z;
    const float* in; unsigned short* out; int R, C, r0, c0;
    if (z < 4) {
        in = w1 + (size_t)z * DD * HH; out = w1t + (size_t)z * DD * HH;
        R = DD; C = HH; r0 = blockIdx.y * 32; c0 = blockIdx.x * 32;
    } else {
        in = w2 + (size_t)(z - 4) * HH * DD; out = w2t + (size_t)(z - 4) * HH * DD;
        R = HH; C = DD; r0 = blockIdx.x * 32; c0 = blockIdx.y * 32;
    }
    __shared__ float tile[32][33];
    int tx = threadIdx.x & 31, ty = threadIdx.x >> 5;
#pragma unroll
    for (int it = 0; it < 4; it++) {
        int r = ty + it * 8;
        tile[r][tx] = in[(size_t)(r0 + r) * C + c0 + tx];
    }
    __syncthreads();
#pragma unroll
    for (int it = 0; it < 4; it++) {
        int r = ty + it * 8;
        out[(size_t)(c0 + r) * R + r0 + tx] = f2bf(tile[tx][r]);
    }
}

// ------- gating (fp32 logits, exact top-2, softmax over top-2) + fused h->bf16 cast -------
__global__ void k_gate(const float* __restrict__ h, const float* __restrict__ wg,
                       int* __restrict__ sel, float* __restrict__ gv,
                       unsigned short* __restrict__ hb) {
    int wid = threadIdx.x >> 6, lane = threadIdx.x & 63;
    int n = blockIdx.x * 4 + wid;
    const float* hr = h + (size_t)n * DD;
    int d0 = lane * 8;
    float hv[8];
    *(float4*)(hv)     = *(const float4*)(hr + d0);
    *(float4*)(hv + 4) = *(const float4*)(hr + d0 + 4);
    // fused cast: this lane owns h[n][d0..d0+7]
    unsigned short tmp[8];
#pragma unroll
    for (int j = 0; j < 8; j++) tmp[j] = f2bf(hv[j]);
    *(uint4*)(hb + (size_t)n * DD + d0) = *(const uint4*)tmp;

    float a0 = 0.f, a1 = 0.f, a2 = 0.f, a3 = 0.f;
#pragma unroll
    for (int j = 0; j < 8; j++) {
        float4 w = *(const float4*)(wg + (size_t)(d0 + j) * 4);
        a0 += hv[j] * w.x; a1 += hv[j] * w.y; a2 += hv[j] * w.z; a3 += hv[j] * w.w;
    }
#pragma unroll
    for (int off = 32; off; off >>= 1) {
        a0 += __shfl_xor(a0, off);
        a1 += __shfl_xor(a1, off);
        a2 += __shfl_xor(a2, off);
        a3 += __shfl_xor(a3, off);
    }
    if (lane == 0) {
        float v[4] = {a0, a1, a2, a3};
        int e0 = 0; float b = v[0];
#pragma unroll
        for (int e = 1; e < 4; e++) if (v[e] > b) { b = v[e]; e0 = e; }
        int e1 = -1; float b2 = -1e30f;
#pragma unroll
        for (int e = 0; e < 4; e++) if (e != e0 && v[e] > b2) { b2 = v[e]; e1 = e; }
        float x = expf(b2 - b);
        float s = 1.f + x;
        sel[2 * n] = e0; sel[2 * n + 1] = e1;
        gv[2 * n] = 1.f / s; gv[2 * n + 1] = x / s;
    }
}

// ---------------- single-block scan: counts -> offsets -> deterministic slots ----------------
// ctl: [8..11]=expert base, [12]=total
__global__ __launch_bounds__(256) void k_scan(const int* __restrict__ sel, const float* __restrict__ gv,
                                              int* __restrict__ ctl, int* __restrict__ rtok,
                                              float* __restrict__ rgte, int* __restrict__ slotof) {
    __shared__ int cnt[4][256];
    __shared__ int ebase[4];
    int t = threadIdx.x;
    int c[4] = {0, 0, 0, 0};
    int selloc[64];
#pragma unroll 4
    for (int i = 0; i < 64; i++) {
        int s = sel[t * 64 + i];
        selloc[i] = s;
        c[s]++;
    }
#pragma unroll
    for (int e = 0; e < 4; e++) cnt[e][t] = c[e];
    __syncthreads();
    for (int step = 1; step < 256; step <<= 1) {
        int v[4];
#pragma unroll
        for (int e = 0; e < 4; e++) v[e] = (t >= step) ? cnt[e][t - step] : 0;
        __syncthreads();
#pragma unroll
        for (int e = 0; e < 4; e++) cnt[e][t] += v[e];
        __syncthreads();
    }
    if (t == 0) {
        int o = 0;
#pragma unroll
        for (int e = 0; e < 4; e++) { ebase[e] = o; ctl[8 + e] = o; o += cnt[e][255]; }
        ctl[12] = o;
    }
    __syncthreads();
    int pos[4];
#pragma unroll
    for (int e = 0; e < 4; e++) pos[e] = ebase[e] + cnt[e][t] - c[e];  // exclusive prefix
#pragma unroll 4
    for (int i = 0; i < 64; i++) {
        int idx = t * 64 + i;          // = 2*n + k
        int e = selloc[i];
        int s = pos[e]++;
        rtok[s] = idx >> 1;
        rgte[s] = gv[idx];
        slotof[idx] = s;
    }
}

// ---------------- grouped GEMM 1: mid = relu(gather(h) @ w1[e] + b1[e]) ----------------
__global__ __launch_bounds__(256) void k_ffn1(
    const unsigned short* __restrict__ hb, const unsigned short* __restrict__ w1t,
    const float* __restrict__ b1, const int* __restrict__ ctl,
    const int* __restrict__ rtok, unsigned short* __restrict__ mid) {
    int e = blockIdx.z;
    int base = ctl[8 + e];
    int cnt = ctl[9 + e] - base;
    int m0 = blockIdx.y * 128;
    if (m0 >= cnt) return;
    int n0 = blockIdx.x * 128;

    __shared__ unsigned short smem[SMEM_ELEMS];
    __shared__ int toks[128];
    unsigned short* As = smem;          // [128][64], swizzled chunks
    unsigned short* Bs = smem + 8192;

    int t = threadIdx.x;
    if (t < 128) {
        int r = m0 + t; if (r >= cnt) r = cnt - 1;
        toks[t] = rtok[base + r];
    }
    __syncthreads();

    const unsigned short* wB = w1t + (size_t)e * HH * DD;
    int wid = t >> 6, lane = t & 63;
    int wm = (wid & 1) * 64, wn = (wid >> 1) * 64;
    int lrow = lane & 15, quad = lane >> 4;

    // staging: wave stages 8 rows (128B each) per call, 4 calls per matrix.
    // swizzle: LDS slot (row, p) holds global chunk (p - row) & 7.
    const unsigned short* gA[4]; const unsigned short* gB[4];
    unsigned short* lA[4]; unsigned short* lB[4];
    int srow8 = lane >> 3, sch = lane & 7;
#pragma unroll
    for (int c = 0; c < 4; c++) {
        int row = wid * 32 + c * 8 + srow8;
        int cg = (sch - row) & 7;
        gA[c] = hb + (size_t)toks[row] * DD + cg * 8;
        gB[c] = wB + (size_t)(n0 + row) * DD + cg * 8;
        lA[c] = As + row * BK + sch * 8;
        lB[c] = Bs + row * BK + sch * 8;
    }

    floatx4 acc[4][4];
#pragma unroll
    for (int i = 0; i < 4; i++)
#pragma unroll
        for (int j = 0; j < 4; j++) acc[i][j] = (floatx4)0.f;

    for (int kk = 0; kk < DD; kk += BK) {
#pragma unroll
        for (int c = 0; c < 4; c++) {
            gld_lds16(gA[c] + kk, lA[c]);
            gld_lds16(gB[c] + kk, lB[c]);
        }
        __syncthreads();
#pragma unroll
        for (int ks = 0; ks < 2; ks++) {
            short8 af[4], bf[4];
#pragma unroll
            for (int i = 0; i < 4; i++) {
                int row = wm + 16 * i + lrow;
                af[i] = *(const short8*)&As[row * BK + (((ks << 2) + quad + row) & 7) * 8];
            }
#pragma unroll
            for (int j = 0; j < 4; j++) {
                int row = wn + 16 * j + lrow;
                bf[j] = *(const short8*)&Bs[row * BK + (((ks << 2) + quad + row) & 7) * 8];
            }
#pragma unroll
            for (int i = 0; i < 4; i++)
#pragma unroll
                for (int j = 0; j < 4; j++)
                    acc[i][j] = __builtin_amdgcn_mfma_f32_16x16x32_bf16(af[i], bf[j], acc[i][j], 0, 0, 0);
        }
        __syncthreads();
    }

    // epilogue: bias + relu -> LDS repack -> coalesced dwordx4 stores
#pragma unroll
    for (int j = 0; j < 4; j++) {
        int col = wn + 16 * j + lrow;
        float bias = b1[e * HH + n0 + col];
#pragma unroll
        for (int i = 0; i < 4; i++) {
#pragma unroll
            for (int r = 0; r < 4; r++) {
                int m = wm + 16 * i + quad * 4 + r;
                float v = acc[i][j][r] + bias;
                v = v > 0.f ? v : 0.f;
                smem[m * RP + col] = f2bf(v);
            }
        }
    }
    __syncthreads();
    {
        int row = t >> 1, half = t & 1;
        if (m0 + row < cnt) {
            unsigned short* dst = mid + (size_t)(base + m0 + row) * HH + n0 + half * 64;
            const unsigned short* src = smem + row * RP + half * 64;
#pragma unroll
            for (int it = 0; it < 8; it++)
                *(uint4*)(dst + it * 8) = *(const uint4*)(src + it * 8);
        }
    }
}

// ---------------- grouped GEMM 2: ybuf[slot] = gate * (mid @ w2[e] + b2[e]) ----------------
__global__ __launch_bounds__(256) void k_ffn2(
    const unsigned short* __restrict__ mid, const unsigned short* __restrict__ w2t,
    const float* __restrict__ b2, const int* __restrict__ ctl,
    const float* __restrict__ rgte, unsigned short* __restrict__ ybuf) {
    int e = blockIdx.z;
    int base = ctl[8 + e];
    int cnt = ctl[9 + e] - base;
    int m0 = blockIdx.y * 128;
    if (m0 >= cnt) return;
    int n0 = blockIdx.x * 128;

    __shared__ unsigned short smem[SMEM_ELEMS];
    __shared__ float gts[128];
    unsigned short* As = smem;
    unsigned short* Bs = smem + 8192;

    int t = threadIdx.x;
    if (t < 128) {
        int r = m0 + t; if (r >= cnt) r = cnt - 1;
        gts[t] = rgte[base + r];
    }
    __syncthreads();

    const unsigned short* wB = w2t + (size_t)e * DD * HH;
    int wid = t >> 6, lane = t & 63;
    int wm = (wid & 1) * 64, wn = (wid >> 1) * 64;
    int lrow = lane & 15, quad = lane >> 4;

    const unsigned short* gA[4]; const unsigned short* gB[4];
    unsigned short* lA[4]; unsigned short* lB[4];
    int srow8 = lane >> 3, sch = lane & 7;
#pragma unroll
    for (int c = 0; c < 4; c++) {
        int row = wid * 32 + c * 8 + srow8;
        int cg = (sch - row) & 7;
        int ra = m0 + row; if (ra >= cnt) ra = cnt - 1;
        gA[c] = mid + (size_t)(base + ra) * HH + cg * 8;
        gB[c] = wB + (size_t)(n0 + row) * HH + cg * 8;
        lA[c] = As + row * BK + sch * 8;
        lB[c] = Bs + row * BK + sch * 8;
    }

    floatx4 acc[4][4];
#pragma unroll
    for (int i = 0; i < 4; i++)
#pragma unroll
        for (int j = 0; j < 4; j++) acc[i][j] = (floatx4)0.f;

    for (int kk = 0; kk < HH; kk += BK) {
#pragma unroll
        for (int c = 0; c < 4; c++) {
            gld_lds16(gA[c] + kk, lA[c]);
            gld_lds16(gB[c] + kk, lB[c]);
        }
        __syncthreads();
#pragma unroll
        for (int ks = 0; ks < 2; ks++) {
            short8 af[4], bf[4];
#pragma unroll
            for (int i = 0; i < 4; i++) {
                int row = wm + 16 * i + lrow;
                af[i] = *(const short8*)&As[row * BK + (((ks << 2) + quad + row) & 7) * 8];
            }
#pragma unroll
            for (int j = 0; j < 4; j++) {
                int row = wn + 16 * j + lrow;
                bf[j] = *(const short8*)&Bs[row * BK + (((ks << 2) + quad + row) & 7) * 8];
            }
#pragma unroll
            for (int i = 0; i < 4; i++)
#pragma unroll
                for (int j = 0; j < 4; j++)
                    acc[i][j] = __builtin_amdgcn_mfma_f32_16x16x32_bf16(af[i], bf[j], acc[i][j], 0, 0, 0);
        }
        __syncthreads();
    }

    // epilogue: bias + gate-scale -> LDS repack -> coalesced stores
#pragma unroll
    for (int j = 0; j < 4; j++) {
        int col = wn + 16 * j + lrow;
        float b2v = b2[e * DD + n0 + col];
#pragma unroll
        for (int i = 0; i < 4; i++) {
#pragma unroll
            for (int r = 0; r < 4; r++) {
                int m = wm + 16 * i + quad * 4 + r;
                float v = (acc[i][j][r] + b2v) * gts[m];
                smem[m * RP + col] = f2bf(v);
            }
        }
    }
    __syncthreads();
    {
        int row = t >> 1, half = t & 1;
        if (m0 + row < cnt) {
            unsigned short* dst = ybuf + (size_t)(base + m0 + row) * DD + n0 + half * 64;
            const unsigned short* src = smem + row * RP + half * 64;
#pragma unroll
            for (int it = 0; it < 8; it++)
                *(uint4*)(dst + it * 8) = *(const uint4*)(src + it * 8);
        }
    }
}

// ---------------- combine: out[n] = ybuf[slot(n,0)] + ybuf[slot(n,1)] ----------------
__global__ void k_combine(const unsigned short* __restrict__ ybuf, const int* __restrict__ slotof,
                          float* __restrict__ out) {
    int n = blockIdx.x * 2 + (threadIdx.x >> 7);
    int c = (threadIdx.x & 127) * 4;
    int sA = slotof[2 * n], sB = slotof[2 * n + 1];
    ushort4 a = *(const ushort4*)(ybuf + (size_t)sA * DD + c);
    ushort4 b = *(const ushort4*)(ybuf + (size_t)sB * DD + c);
    float4 o;
    o.x = bf2f(a.x) + bf2f(b.x);
    o.y = bf2f(a.y) + bf2f(b.y);
    o.z = bf2f(a.z) + bf2f(b.z);
    o.w = bf2f(a.w) + bf2f(b.w);
    *(float4*)(out + (size_t)n * DD + c) = o;
}

extern "C" void kernel_launch(void* const* d_in, const int* in_sizes, int n_in,
                              void* d_out, int out_size, void* d_ws, size_t ws_size,
                              hipStream_t stream) {
    const float* h  = (const float*)d_in[0];
    const float* wg = (const float*)d_in[1];
    const float* w1 = (const float*)d_in[2];
    const float* b1 = (const float*)d_in[3];
    const float* w2 = (const float*)d_in[4];
    const float* b2 = (const float*)d_in[5];
    float* out = (float*)d_out;

    char* ws = (char*)d_ws;
    size_t off = 0;
    auto alloc = [&](size_t bytes) -> void* {
        void* p = ws + off;
        off += (bytes + 255) & ~(size_t)255;
        return p;
    };
    unsigned short* hb  = (unsigned short*)alloc((size_t)NT * DD * 2);        // dead after ffn1
    unsigned short* w1t = (unsigned short*)alloc((size_t)NE * HH * DD * 2);   // dead after ffn1
    unsigned short* w2t = (unsigned short*)alloc((size_t)NE * DD * HH * 2);
    int*   sel    = (int*)alloc((size_t)NT * 2 * 4);
    float* gv     = (float*)alloc((size_t)NT * 2 * 4);
    int*   ctl    = (int*)alloc(256);
    int*   rtok   = (int*)alloc((size_t)NT * 2 * 4);
    float* rgte   = (float*)alloc((size_t)NT * 2 * 4);
    int*   slotof = (int*)alloc((size_t)NT * 2 * 4);
    unsigned short* mid = (unsigned short*)alloc((size_t)NT * 2 * HH * 2);
    // ybuf [NT*2][DD] bf16 (16.7 MB) aliases hb+w1t (16.7 MB), both dead before ffn2 runs
    unsigned short* ybuf = (unsigned short*)ws;

    k_transpose_cast<<<dim3(HH / 32, DD / 32, 2 * NE), 256, 0, stream>>>(w1, w1t, w2, w2t);
    k_gate<<<dim3(NT / 4), 256, 0, stream>>>(h, wg, sel, gv, hb);
    k_scan<<<1, 256, 0, stream>>>(sel, gv, ctl, rtok, rgte, slotof);
    k_ffn1<<<dim3(HH / 128, NT / 128, NE), 256, 0, stream>>>(hb, w1t, b1, ctl, rtok, mid);
    k_ffn2<<<dim3(DD / 128, NT / 128, NE), 256, 0, stream>>>(mid, w2t, b2, ctl, rgte, ybuf);
    k_combine<<<dim3(NT / 2), 256, 0, stream>>>(ybuf, slotof, out);
}